// Round 22
// baseline (331.033 us; speedup 1.0000x reference)
//
#include <hip/hip_runtime.h>

#define VN     5023
#define NBETA  150
#define NBP    152          // padded K: 0..149 betas-dirs, 150 = v_template, 151 = 0
#define NL4    38           // NBP/4: float4-grouped K index
#define VP     5024         // vertex-padded stride for transposed layout
#define NBATCH 1024
#define N3     15069        // V*3
#define BT     16           // batches per block in K3 (2 chunks of 8)
#define BC     8            // chunk size

// ---- K0: build TRANSPOSED panel sdpT4[c][l4][v] (float4 = K-values 4l4..4l4+3). ----
__global__ void k0_t4(const float* __restrict__ sd, const float* __restrict__ vt,
                      float4* __restrict__ sdpT4) {
    int i = blockIdx.x * 256 + threadIdx.x;
    if (i >= 3 * NL4 * VP) return;
    int c   = i / (NL4 * VP);
    int rem = i - c * (NL4 * VP);
    int l4  = rem / VP;
    int v   = rem - l4 * VP;
    float4 out = make_float4(0.f, 0.f, 0.f, 0.f);
    if (v < VN) {
        int row = v * 3 + c;
        float vals[4];
#pragma unroll
        for (int q = 0; q < 4; q++) {
            int ll = l4 * 4 + q;
            vals[q] = (ll < NBETA) ? sd[row * NBETA + ll]
                     : ((ll == NBETA) ? vt[row] : 0.f);
        }
        out = make_float4(vals[0], vals[1], vals[2], vals[3]);
    }
    sdpT4[i] = out;   // consecutive i -> consecutive v: coalesced write
}

// ---- K1: JS[j3c][4*l4+q] = sum_v jr[j,v] * sdpT4[c][l4][v].q ----
__global__ void k1_t4(const float* __restrict__ jr, const float4* __restrict__ sdpT4,
                      float* __restrict__ JS) {
    int j3c = blockIdx.x, l4 = blockIdx.y;
    int j = j3c / 3, c = j3c - 3 * j;
    int t = threadIdx.x;
    const float4* col = sdpT4 + (size_t)(c * NL4 + l4) * VP;
    float4 acc = make_float4(0.f, 0.f, 0.f, 0.f);
    for (int v = t; v < VN; v += 256) {
        float w = jr[j * VN + v];
        float4 s = col[v];
        acc.x += w * s.x; acc.y += w * s.y; acc.z += w * s.z; acc.w += w * s.w;
    }
    __shared__ float4 red[256];
    red[t] = acc; __syncthreads();
    for (int s = 128; s > 0; s >>= 1) {
        if (t < s) {
            red[t].x += red[t + s].x; red[t].y += red[t + s].y;
            red[t].z += red[t + s].z; red[t].w += red[t + s].w;
        }
        __syncthreads();
    }
    if (t == 0) {
        JS[j3c * NBP + l4 * 4 + 0] = red[0].x;
        JS[j3c * NBP + l4 * 4 + 1] = red[0].y;
        JS[j3c * NBP + l4 * 4 + 2] = red[0].z;
        JS[j3c * NBP + l4 * 4 + 3] = red[0].w;
    }
}

// ---- rodrigues (matches reference eps semantics) ----
__device__ __forceinline__ void rodrigues3(float x, float y, float z, float* R) {
    float ax = x + 1e-8f, ay = y + 1e-8f, az = z + 1e-8f;
    float ang = sqrtf(ax * ax + ay * ay + az * az);
    float inv = 1.0f / ang;
    float ux = x * inv, uy = y * inv, uz = z * inv;
    float co = cosf(ang), si = sinf(ang), t1 = 1.0f - co;
    float K[9] = {0.f, -uz, uy,  uz, 0.f, -ux,  -uy, ux, 0.f};
    float K2[9];
#pragma unroll
    for (int r = 0; r < 3; r++)
#pragma unroll
        for (int cc = 0; cc < 3; cc++) {
            float a = 0.f;
#pragma unroll
            for (int k = 0; k < 3; k++) a += K[r * 3 + k] * K[k * 3 + cc];
            K2[r * 3 + cc] = a;
        }
#pragma unroll
    for (int i = 0; i < 9; i++) {
        float e = (i == 0 || i == 4 || i == 8) ? 1.f : 0.f;
        R[i] = e + si * K[i] + t1 * K2[i];
    }
}

// ---- K2: per-batch betas (col150=1, col151=0), joints = JS.sB, chain, rel, pf9 ----
__global__ void k2_pose(const float* __restrict__ shp, const float* __restrict__ expr,
                        const float* __restrict__ pose, const float* __restrict__ JS,
                        float* __restrict__ betasF, float* __restrict__ pf9,
                        float* __restrict__ rel) {
    int b = blockIdx.x;
    int tt = threadIdx.x;
    __shared__ float sB[NBP];
    __shared__ float sJ[15];
    for (int l = tt; l < NBP; l += 64) {
        float val = 0.0f;
        if (l < 100) val = shp[b * 100 + l];
        else if (l < 150) val = expr[b * 50 + (l - 100)];
        else if (l == 150) val = 1.0f;   // picks up v_template / Jt columns
        sB[l] = val;
        betasF[b * NBP + l] = val;
    }
    __syncthreads();
    if (tt < 15) {
        float acc = 0.0f;
        const float* row = JS + tt * NBP;
        for (int l = 0; l < NBP; ++l) acc += row[l] * sB[l];
        sJ[tt] = acc;
    }
    __syncthreads();
    if (tt == 0) {
        float p[6];
#pragma unroll
        for (int i = 0; i < 6; i++) p[i] = pose[b * 6 + i];
        float R0[9], RJ[9];
        rodrigues3(p[0], p[1], p[2], R0);
        rodrigues3(p[3], p[4], p[5], RJ);
        float Jm[5][3];
#pragma unroll
        for (int jj = 0; jj < 5; jj++)
#pragma unroll
            for (int cc = 0; cc < 3; cc++) Jm[jj][cc] = sJ[jj * 3 + cc];
        float rj[5][3];
#pragma unroll
        for (int cc = 0; cc < 3; cc++) {
            rj[0][cc] = Jm[0][cc];
            rj[1][cc] = Jm[1][cc] - Jm[0][cc];
            rj[2][cc] = Jm[2][cc] - Jm[1][cc];
            rj[3][cc] = Jm[3][cc] - Jm[1][cc];
            rj[4][cc] = Jm[4][cc] - Jm[1][cc];
        }
        float tw[5][3];
#pragma unroll
        for (int cc = 0; cc < 3; cc++) tw[0][cc] = rj[0][cc];
#pragma unroll
        for (int cc = 0; cc < 3; cc++)
            tw[1][cc] = R0[cc * 3 + 0] * rj[1][0] + R0[cc * 3 + 1] * rj[1][1] + R0[cc * 3 + 2] * rj[1][2] + tw[0][cc];
#pragma unroll
        for (int jj = 2; jj < 5; jj++)
#pragma unroll
            for (int cc = 0; cc < 3; cc++)
                tw[jj][cc] = R0[cc * 3 + 0] * rj[jj][0] + R0[cc * 3 + 1] * rj[jj][1] + R0[cc * 3 + 2] * rj[jj][2] + tw[1][cc];
        float R2w[9];
#pragma unroll
        for (int r = 0; r < 3; r++)
#pragma unroll
            for (int cc = 0; cc < 3; cc++) {
                float a = 0.f;
#pragma unroll
                for (int k = 0; k < 3; k++) a += R0[r * 3 + k] * RJ[k * 3 + cc];
                R2w[r * 3 + cc] = a;
            }
        float* ro = rel + b * 80;
#pragma unroll
        for (int jj = 0; jj < 5; jj++) {
            const float* Rw = (jj == 2) ? R2w : R0;
#pragma unroll
            for (int rr = 0; rr < 3; rr++) {
                ro[jj * 16 + rr * 4 + 0] = Rw[rr * 3 + 0];
                ro[jj * 16 + rr * 4 + 1] = Rw[rr * 3 + 1];
                ro[jj * 16 + rr * 4 + 2] = Rw[rr * 3 + 2];
                float tj = Rw[rr * 3 + 0] * Jm[jj][0] + Rw[rr * 3 + 1] * Jm[jj][1] + Rw[rr * 3 + 2] * Jm[jj][2];
                ro[jj * 16 + rr * 4 + 3] = tw[jj][rr] - tj;
            }
            ro[jj * 16 + 12] = 0.f; ro[jj * 16 + 13] = 0.f; ro[jj * 16 + 14] = 0.f; ro[jj * 16 + 15] = 1.f;
        }
        float* pf = pf9 + b * 12;
#pragma unroll
        for (int e = 0; e < 9; e++) pf[e] = RJ[e] - ((e == 0 || e == 4 || e == 8) ? 1.f : 0.f);
        pf[9] = 0.f; pf[10] = 0.f; pf[11] = 0.f;
    }
}

// ---- epilogue for one batch chunk (BC batches) ----
__device__ __forceinline__ void epilogue8(const float acc[3][BC], int b0c, int v,
                                          const float* __restrict__ wj,
                                          const float pdv[9][3],
                                          const float* __restrict__ pf9,
                                          const float* __restrict__ rel,
                                          float* __restrict__ outv,
                                          float* __restrict__ outT) {
#pragma unroll
    for (int bb = 0; bb < BC; bb++) {
        int b = b0c + bb;
        const float* pf = pf9 + b * 12;   // uniform -> scalar loads
        const float* rb = rel + b * 80;   // uniform -> scalar loads
        float vp[3];
#pragma unroll
        for (int c = 0; c < 3; c++) {
            float x = acc[c][bb];
#pragma unroll
            for (int k = 0; k < 9; k++) x += pf[k] * pdv[k][c];
            vp[c] = x;
        }
        float T[16];
#pragma unroll
        for (int e = 0; e < 16; e++) T[e] = 0.0f;
#pragma unroll
        for (int j = 0; j < 5; j++) {
            float w = wj[j];
            const float4 r0 = *(const float4*)(rb + j * 16 + 0);
            const float4 r1 = *(const float4*)(rb + j * 16 + 4);
            const float4 r2 = *(const float4*)(rb + j * 16 + 8);
            const float4 r3 = *(const float4*)(rb + j * 16 + 12);
            T[0]  += w * r0.x;  T[1]  += w * r0.y;  T[2]  += w * r0.z;  T[3]  += w * r0.w;
            T[4]  += w * r1.x;  T[5]  += w * r1.y;  T[6]  += w * r1.z;  T[7]  += w * r1.w;
            T[8]  += w * r2.x;  T[9]  += w * r2.y;  T[10] += w * r2.z;  T[11] += w * r2.w;
            T[12] += w * r3.x;  T[13] += w * r3.y;  T[14] += w * r3.z;  T[15] += w * r3.w;
        }
        float vo[3];
#pragma unroll
        for (int rr = 0; rr < 3; rr++)
            vo[rr] = T[rr * 4 + 0] * vp[0] + T[rr * 4 + 1] * vp[1] + T[rr * 4 + 2] * vp[2] + T[rr * 4 + 3];

        size_t vbase = (size_t)b * VN + v;
        float* pv = outv + vbase * 3;
        pv[0] = vo[0];
        pv[1] = vo[1];
        pv[2] = vo[2];
        float4* pT = (float4*)(outT + vbase * 16);
        pT[0] = make_float4(T[0],  T[1],  T[2],  T[3]);
        pT[1] = make_float4(T[4],  T[5],  T[6],  T[7]);
        pT[2] = make_float4(T[8],  T[9],  T[10], T[11]);
        pT[3] = make_float4(T[12], T[13], T[14], T[15]);
    }
}

// ---- K3: fused GEMM + epilogue in TWO chunks of 8 batches ----
// Chunk 2's ~8K cycles of FMA overlap chunk 1's ~40-store drain WITHIN the wave
// (store-drain hypothesis: at 2.2 waves/SIMD, end-of-wave store bursts block on
// full vmem queues with no sibling compute to cover them). sdp is re-read once
// (L1/L2-resident second pass). wj/pdv loaded once, live across chunk 2
// (VGPR cap 256 via launch_bounds -> no spill; round-21 got 100 granted).
__global__ void __launch_bounds__(128, 2)
k3_main(const float4* __restrict__ sdpT4, const float* __restrict__ pd,
        const float* __restrict__ lw,
        const float* __restrict__ betasF, const float* __restrict__ pf9,
        const float* __restrict__ rel,
        float* __restrict__ outv, float* __restrict__ outT) {
    int tid = threadIdx.x;
    int v = blockIdx.x * 128 + tid;
    bool ok = v < VN;
    int vc = ok ? v : VN - 1;
    int b0 = blockIdx.y * BT;

    const float4* sp = sdpT4 + vc;

    float wj[5], pdv[9][3];
    bool epiLoaded = false;

#pragma unroll
    for (int chunk = 0; chunk < 2; chunk++) {
        int b0c = b0 + chunk * BC;
        float acc[3][BC];
#pragma unroll
        for (int c = 0; c < 3; c++)
#pragma unroll
            for (int bb = 0; bb < BC; bb++) acc[c][bb] = 0.0f;

        // prologue prefetch
        float4 nA0 = sp[(size_t)(0 * NL4) * VP],  nA1 = sp[(size_t)(0 * NL4 + 1) * VP];
        float4 nB0 = sp[(size_t)(1 * NL4) * VP],  nB1 = sp[(size_t)(1 * NL4 + 1) * VP];
        float4 nC0 = sp[(size_t)(2 * NL4) * VP],  nC1 = sp[(size_t)(2 * NL4 + 1) * VP];

#pragma unroll 1
        for (int l0 = 0; l0 < NBP; l0 += 8) {
            float4 a0 = nA0, a1 = nA1, b0q = nB0, b1q = nB1, c0q = nC0, c1q = nC1;
            int i0n = (l0 + 8 < NBP) ? ((l0 + 8) >> 2) : 0;
            nA0 = sp[(size_t)(0 * NL4 + i0n) * VP];  nA1 = sp[(size_t)(0 * NL4 + i0n + 1) * VP];
            nB0 = sp[(size_t)(1 * NL4 + i0n) * VP];  nB1 = sp[(size_t)(1 * NL4 + i0n + 1) * VP];
            nC0 = sp[(size_t)(2 * NL4 + i0n) * VP];  nC1 = sp[(size_t)(2 * NL4 + i0n + 1) * VP];

            float s0[8] = {a0.x, a0.y, a0.z, a0.w, a1.x, a1.y, a1.z, a1.w};
            float s1[8] = {b0q.x, b0q.y, b0q.z, b0q.w, b1q.x, b1q.y, b1q.z, b1q.w};
            float s2[8] = {c0q.x, c0q.y, c0q.z, c0q.w, c1q.x, c1q.y, c1q.z, c1q.w};
#pragma unroll
            for (int bb = 0; bb < BC; bb++) {
                const float* brow = betasF + (size_t)(b0c + bb) * NBP + l0;  // uniform -> scalar
                const float4 be0 = *(const float4*)(brow);
                const float4 be1 = *(const float4*)(brow + 4);
                float be[8] = {be0.x, be0.y, be0.z, be0.w, be1.x, be1.y, be1.z, be1.w};
#pragma unroll
                for (int k = 0; k < 8; k++) {
                    acc[0][bb] += be[k] * s0[k];
                    acc[1][bb] += be[k] * s1[k];
                    acc[2][bb] += be[k] * s2[k];
                }
            }
        }

        if (ok) {
            if (!epiLoaded) {
                epiLoaded = true;
#pragma unroll
                for (int j = 0; j < 5; j++) wj[j] = lw[v * 5 + j];
#pragma unroll
                for (int k = 0; k < 9; k++)
#pragma unroll
                    for (int c = 0; c < 3; c++) pdv[k][c] = pd[(size_t)(9 + k) * N3 + v * 3 + c];
            }
            epilogue8(acc, b0c, v, wj, pdv, pf9, rel, outv, outT);
        }
    }
}

// ---------------- launch ----------------
extern "C" void kernel_launch(void* const* d_in, const int* in_sizes, int n_in,
                              void* d_out, int out_size, void* d_ws, size_t ws_size,
                              hipStream_t stream) {
    const float* shp  = (const float*)d_in[0];  // [1024,100]
    const float* expr = (const float*)d_in[1];  // [1024,50]
    const float* pose = (const float*)d_in[2];  // [1024,6]
    const float* vt   = (const float*)d_in[3];  // [5023,3]
    const float* sd   = (const float*)d_in[4];  // [5023,3,150]
    const float* pd   = (const float*)d_in[5];  // [36,15069]
    const float* jr   = (const float*)d_in[6];  // [5,5023]
    const float* lw   = (const float*)d_in[7];  // [5023,5]

    float* outv = (float*)d_out;
    float* outT = outv + (size_t)NBATCH * VN * 3;

    char* w = (char*)d_ws;
    const size_t SDPT_B  = (size_t)3 * NL4 * VP * 16;       // 9,163,776
    const size_t JS_B    = 15 * NBP * 4;                    // 9,120
    const size_t BETAS_B = (size_t)NBATCH * NBP * 4;        // 622,592
    const size_t PF9_B   = (size_t)NBATCH * 12 * 4;         // 49,152
    float4* sdpT4 = (float4*)w;
    float* JS     = (float*)(w + SDPT_B);
    float* betasF = (float*)(w + SDPT_B + JS_B);
    float* pf9    = (float*)(w + SDPT_B + JS_B + BETAS_B);
    float* rel    = (float*)(w + SDPT_B + JS_B + BETAS_B + PF9_B);

    k0_t4<<<(3 * NL4 * VP + 255) / 256, 256, 0, stream>>>(sd, vt, sdpT4);
    k1_t4<<<dim3(15, NL4), 256, 0, stream>>>(jr, sdpT4, JS);
    k2_pose<<<NBATCH, 64, 0, stream>>>(shp, expr, pose, JS, betasF, pf9, rel);
    k3_main<<<dim3(40, NBATCH / BT), 128, 0, stream>>>(sdpT4, pd, lw, betasF, pf9, rel, outv, outT);
}

// Round 23
// 255.773 us; speedup vs baseline: 1.2942x; 1.2942x over previous
//
#include <hip/hip_runtime.h>
#include <hip/hip_bf16.h>

#define VN     5023
#define NBATCH 1024
#define N3     15069        // V*3
#define NPAD   15168        // N3 padded to 192*79
#define NKG    20           // k-groups of 8 (K=160)

typedef short bf16x8 __attribute__((ext_vector_type(8)));
typedef float f32x4  __attribute__((ext_vector_type(4)));

__device__ __forceinline__ short f2bf(float x) {
    __hip_bfloat16 h = __float2bfloat16(x);
    return *reinterpret_cast<short*>(&h);
}

// ---- K0: pack sdp (+ v_template at k=150) into bf16 B-panels sdpB[kg][n] ----
__global__ void k0_bf(const float* __restrict__ sd, const float* __restrict__ vt,
                      bf16x8* __restrict__ sdpB) {
    int i = blockIdx.x * 256 + threadIdx.x;
    if (i >= NKG * NPAD) return;
    int kg = i / NPAD, n = i - kg * NPAD;
    int kbase = (kg >> 2) * 32 + (kg & 3) * 8;
    bf16x8 out;
#pragma unroll
    for (int e = 0; e < 8; e++) {
        int k = kbase + e;
        float val = 0.f;
        if (n < N3) {
            if (k < 150)       val = sd[(size_t)n * 150 + k];
            else if (k == 150) val = vt[n];
        }
        out[e] = f2bf(val);
    }
    sdpB[i] = out;
}

// ---- K1: JS[j3c][l] = sum_v jr[j,v]*sd / vt (f32-exact joints) ----
__global__ void k1_js(const float* __restrict__ jr, const float* __restrict__ sd,
                      const float* __restrict__ vt, float* __restrict__ JS) {
    int j3c = blockIdx.x;
    int j = j3c / 3, c = j3c - 3 * j;
    int l = threadIdx.x;
    if (l >= 152) return;
    int v0 = blockIdx.y * 157, v1 = min(v0 + 157, VN);
    float acc = 0.0f;
    for (int v = v0; v < v1; ++v) {
        float w = jr[j * VN + v];
        float s = (l < 150) ? sd[(size_t)(v * 3 + c) * 150 + l]
                            : ((l == 150) ? vt[v * 3 + c] : 0.f);
        acc += w * s;
    }
    atomicAdd(&JS[j3c * 152 + l], acc);
}

// ---- rodrigues (matches reference eps semantics) ----
__device__ __forceinline__ void rodrigues3(float x, float y, float z, float* R) {
    float ax = x + 1e-8f, ay = y + 1e-8f, az = z + 1e-8f;
    float ang = sqrtf(ax * ax + ay * ay + az * az);
    float inv = 1.0f / ang;
    float ux = x * inv, uy = y * inv, uz = z * inv;
    float co = cosf(ang), si = sinf(ang), t1 = 1.0f - co;
    float K[9] = {0.f, -uz, uy,  uz, 0.f, -ux,  -uy, ux, 0.f};
    float K2[9];
#pragma unroll
    for (int r = 0; r < 3; r++)
#pragma unroll
        for (int cc = 0; cc < 3; cc++) {
            float a = 0.f;
#pragma unroll
            for (int k = 0; k < 3; k++) a += K[r * 3 + k] * K[k * 3 + cc];
            K2[r * 3 + cc] = a;
        }
#pragma unroll
    for (int i = 0; i < 9; i++) {
        float e = (i == 0 || i == 4 || i == 8) ? 1.f : 0.f;
        R[i] = e + si * K[i] + t1 * K2[i];
    }
}

// ---- K2: betas -> bf16 A-panels; joints; chain; rel; pf9 ----
__global__ void k2_pose(const float* __restrict__ shp, const float* __restrict__ expr,
                        const float* __restrict__ pose, const float* __restrict__ JS,
                        bf16x8* __restrict__ betasA, float* __restrict__ pf9,
                        float* __restrict__ rel) {
    int b = blockIdx.x;
    int tt = threadIdx.x;
    __shared__ float sB[152];
    __shared__ float sJ[15];
    for (int l = tt; l < 152; l += 64) {
        float val = 0.0f;
        if (l < 100) val = shp[b * 100 + l];
        else if (l < 150) val = expr[b * 50 + (l - 100)];
        else if (l == 150) val = 1.0f;
        sB[l] = val;
    }
    __syncthreads();
    for (int l = tt; l < 160; l += 64) {
        float val = (l < 152) ? sB[l] : 0.f;
        int kg = (l >> 5) * 4 + ((l >> 3) & 3);
        short* dst = (short*)betasA;
        dst[((size_t)kg * NBATCH + b) * 8 + (l & 7)] = f2bf(val);
    }
    if (tt < 15) {
        float acc = 0.0f;
        const float* row = JS + tt * 152;
        for (int l = 0; l < 152; ++l) acc += row[l] * sB[l];
        sJ[tt] = acc;
    }
    __syncthreads();
    if (tt == 0) {
        float p[6];
#pragma unroll
        for (int i = 0; i < 6; i++) p[i] = pose[b * 6 + i];
        float R0[9], RJ[9];
        rodrigues3(p[0], p[1], p[2], R0);
        rodrigues3(p[3], p[4], p[5], RJ);
        float Jm[5][3];
#pragma unroll
        for (int jj = 0; jj < 5; jj++)
#pragma unroll
            for (int cc = 0; cc < 3; cc++) Jm[jj][cc] = sJ[jj * 3 + cc];
        float rj[5][3];
#pragma unroll
        for (int cc = 0; cc < 3; cc++) {
            rj[0][cc] = Jm[0][cc];
            rj[1][cc] = Jm[1][cc] - Jm[0][cc];
            rj[2][cc] = Jm[2][cc] - Jm[1][cc];
            rj[3][cc] = Jm[3][cc] - Jm[1][cc];
            rj[4][cc] = Jm[4][cc] - Jm[1][cc];
        }
        float tw[5][3];
#pragma unroll
        for (int cc = 0; cc < 3; cc++) tw[0][cc] = rj[0][cc];
#pragma unroll
        for (int cc = 0; cc < 3; cc++)
            tw[1][cc] = R0[cc * 3 + 0] * rj[1][0] + R0[cc * 3 + 1] * rj[1][1] + R0[cc * 3 + 2] * rj[1][2] + tw[0][cc];
#pragma unroll
        for (int jj = 2; jj < 5; jj++)
#pragma unroll
            for (int cc = 0; cc < 3; cc++)
                tw[jj][cc] = R0[cc * 3 + 0] * rj[jj][0] + R0[cc * 3 + 1] * rj[jj][1] + R0[cc * 3 + 2] * rj[jj][2] + tw[1][cc];
        float R2w[9];
#pragma unroll
        for (int r = 0; r < 3; r++)
#pragma unroll
            for (int cc = 0; cc < 3; cc++) {
                float a = 0.f;
#pragma unroll
                for (int k = 0; k < 3; k++) a += R0[r * 3 + k] * RJ[k * 3 + cc];
                R2w[r * 3 + cc] = a;
            }
        float* ro = rel + b * 80;
#pragma unroll
        for (int jj = 0; jj < 5; jj++) {
            const float* Rw = (jj == 2) ? R2w : R0;
#pragma unroll
            for (int rr = 0; rr < 3; rr++) {
                ro[jj * 16 + rr * 4 + 0] = Rw[rr * 3 + 0];
                ro[jj * 16 + rr * 4 + 1] = Rw[rr * 3 + 1];
                ro[jj * 16 + rr * 4 + 2] = Rw[rr * 3 + 2];
                float tj = Rw[rr * 3 + 0] * Jm[jj][0] + Rw[rr * 3 + 1] * Jm[jj][1] + Rw[rr * 3 + 2] * Jm[jj][2];
                ro[jj * 16 + rr * 4 + 3] = tw[jj][rr] - tj;
            }
            ro[jj * 16 + 12] = 0.f; ro[jj * 16 + 13] = 0.f; ro[jj * 16 + 14] = 0.f; ro[jj * 16 + 15] = 1.f;
        }
        float* pf = pf9 + b * 12;
#pragma unroll
        for (int e = 0; e < 9; e++) pf[e] = RJ[e] - ((e == 0 || e == 4 || e == 8) ? 1.f : 0.f);
        pf[9] = 0.f; pf[10] = 0.f; pf[11] = 0.f;
    }
}

// ---- K3: MFMA blend-GEMM -> v_posed (pose blend folded), written IN-PLACE into outv ----
// (round-19-verified MFMA layout; stage writes only 62 MB. Each outv slot is later
// read-then-overwritten by the SAME thread of k4 -> no cross-thread hazard.)
__global__ void __launch_bounds__(256, 2)
k3_vp(const bf16x8* __restrict__ sdpB, const bf16x8* __restrict__ betasA,
      const float* __restrict__ pd, const float* __restrict__ pf9,
      float* __restrict__ vposed) {
    __shared__ float vsh[16][200];

    int tid = threadIdx.x;
    int w = tid >> 6, l = tid & 63;
    int row16 = l & 15, g = l >> 4;
    int b0 = blockIdx.y * 16;
    int n0 = blockIdx.x * 192;

    bf16x8 afr[5];
#pragma unroll
    for (int ks = 0; ks < 5; ks++)
        afr[ks] = betasA[(size_t)(ks * 4 + g) * NBATCH + b0 + row16];

    f32x4 acc0 = {0.f, 0.f, 0.f, 0.f}, acc1 = acc0, acc2 = acc0;
    {
        int ntb = n0 + (w * 3) * 16 + row16;
#pragma unroll
        for (int ks = 0; ks < 5; ks++) {
            size_t base = (size_t)(ks * 4 + g) * NPAD;
            acc0 = __builtin_amdgcn_mfma_f32_16x16x32_bf16(afr[ks], sdpB[base + ntb],      acc0, 0, 0, 0);
            acc1 = __builtin_amdgcn_mfma_f32_16x16x32_bf16(afr[ks], sdpB[base + ntb + 16], acc1, 0, 0, 0);
            acc2 = __builtin_amdgcn_mfma_f32_16x16x32_bf16(afr[ks], sdpB[base + ntb + 32], acc2, 0, 0, 0);
        }
    }
    {
        int nl = (w * 3) * 16 + row16;
#pragma unroll
        for (int r = 0; r < 4; r++) {
            vsh[g * 4 + r][nl]      = acc0[r];
            vsh[g * 4 + r][nl + 16] = acc1[r];
            vsh[g * 4 + r][nl + 32] = acc2[r];
        }
    }

    int v_loc = tid & 63;
    int v = blockIdx.x * 64 + v_loc;
    bool vok = v < VN;
    int vc_ = vok ? v : VN - 1;
    float pdv[9][3];
#pragma unroll
    for (int k = 0; k < 9; k++)
#pragma unroll
        for (int c = 0; c < 3; c++) pdv[k][c] = pd[(size_t)(9 + k) * N3 + vc_ * 3 + c];

    __syncthreads();

#pragma unroll
    for (int i = 0; i < 4; i++) {
        int bl = w * 4 + i;
        int b = b0 + bl;
        const float* pf = pf9 + b * 12;   // wave-uniform -> scalar
        float vp[3];
#pragma unroll
        for (int c = 0; c < 3; c++) {
            float x = vsh[bl][v_loc * 3 + c];
#pragma unroll
            for (int k = 0; k < 9; k++) x += pf[k] * pdv[k][c];
            vp[c] = x;
        }
        if (vok) {
            float* pv = vposed + ((size_t)b * VN + v) * 3;
            pv[0] = vp[0]; pv[1] = vp[1]; pv[2] = vp[2];
        }
    }
}

// ---- K4: streaming LBS: tiny state, one thread per (v,b) pair ----
// Reads vp from outv slot, OVERWRITES it with vo; writes T. k3_T-shape
// (measured ~4 TB/s): block-uniform rel via scalar loads, high occupancy.
__global__ void __launch_bounds__(256, 8)
k4_lbs(const float* __restrict__ lw, const float* __restrict__ rel,
       float* __restrict__ outv, float* __restrict__ outT) {
    int b = blockIdx.y;
    int v = blockIdx.x * 256 + threadIdx.x;
    if (v >= VN) return;
    const float* rb = rel + b * 80;       // block-uniform -> scalar loads

    size_t vbase = (size_t)b * VN + v;
    float* pv = outv + vbase * 3;
    float vp0 = pv[0], vp1 = pv[1], vp2 = pv[2];
    float w0 = lw[v * 5 + 0], w1 = lw[v * 5 + 1], w2 = lw[v * 5 + 2];
    float w3 = lw[v * 5 + 3], w4 = lw[v * 5 + 4];

    float T[16];
#pragma unroll
    for (int e = 0; e < 16; e++)
        T[e] = w0 * rb[e] + w1 * rb[16 + e] + w2 * rb[32 + e] + w3 * rb[48 + e] + w4 * rb[64 + e];

    float vo0 = T[0]  * vp0 + T[1]  * vp1 + T[2]  * vp2 + T[3];
    float vo1 = T[4]  * vp0 + T[5]  * vp1 + T[6]  * vp2 + T[7];
    float vo2 = T[8]  * vp0 + T[9]  * vp1 + T[10] * vp2 + T[11];

    pv[0] = vo0; pv[1] = vo1; pv[2] = vo2;
    float4* pT = (float4*)(outT + vbase * 16);
    pT[0] = make_float4(T[0],  T[1],  T[2],  T[3]);
    pT[1] = make_float4(T[4],  T[5],  T[6],  T[7]);
    pT[2] = make_float4(T[8],  T[9],  T[10], T[11]);
    pT[3] = make_float4(T[12], T[13], T[14], T[15]);
}

// ---------------- launch ----------------
extern "C" void kernel_launch(void* const* d_in, const int* in_sizes, int n_in,
                              void* d_out, int out_size, void* d_ws, size_t ws_size,
                              hipStream_t stream) {
    const float* shp  = (const float*)d_in[0];  // [1024,100]
    const float* expr = (const float*)d_in[1];  // [1024,50]
    const float* pose = (const float*)d_in[2];  // [1024,6]
    const float* vt   = (const float*)d_in[3];  // [5023,3]
    const float* sd   = (const float*)d_in[4];  // [5023,3,150]
    const float* pd   = (const float*)d_in[5];  // [36,15069]
    const float* jr   = (const float*)d_in[6];  // [5,5023]
    const float* lw   = (const float*)d_in[7];  // [5023,5]

    float* outv = (float*)d_out;
    float* outT = outv + (size_t)NBATCH * VN * 3;

    char* w = (char*)d_ws;
    const size_t SDPB_B = (size_t)NKG * NPAD * 16;          // 4,853,760
    const size_t BETA_B = (size_t)NKG * NBATCH * 16;        // 327,680
    const size_t JS_B   = 15 * 152 * 4;                     // 9,120
    const size_t PF9_B  = (size_t)NBATCH * 12 * 4;          // 49,152
    bf16x8* sdpB   = (bf16x8*)w;
    bf16x8* betasA = (bf16x8*)(w + SDPB_B);
    float*  JS     = (float*)(w + SDPB_B + BETA_B);
    float*  pf9    = (float*)(w + SDPB_B + BETA_B + JS_B);
    float*  rel    = (float*)(w + SDPB_B + BETA_B + JS_B + PF9_B);

    hipMemsetAsync(JS, 0, JS_B, stream);
    k0_bf<<<(NKG * NPAD + 255) / 256, 256, 0, stream>>>(sd, vt, sdpB);
    k1_js<<<dim3(15, 32), 192, 0, stream>>>(jr, sd, vt, JS);
    k2_pose<<<NBATCH, 64, 0, stream>>>(shp, expr, pose, JS, betasA, pf9, rel);
    k3_vp<<<dim3(NPAD / 192, NBATCH / 16), 256, 0, stream>>>(sdpB, betasA, pd, pf9, outv);
    k4_lbs<<<dim3((VN + 255) / 256, NBATCH), 256, 0, stream>>>(lw, rel, outv, outT);
}

// Round 24
// 239.361 us; speedup vs baseline: 1.3830x; 1.0686x over previous
//
#include <hip/hip_runtime.h>

#define VN     5023
#define NBETA  150
#define NBP    152          // padded K: 0..149 betas-dirs, 150 = v_template, 151 = 0
#define NL4    38           // NBP/4: float4-grouped K index
#define VP     5024         // vertex-padded stride for transposed layout
#define NBATCH 1024
#define N3     15069        // V*3
#define BT     16           // batches per block in K3

// ---- K0: build TRANSPOSED panel sdpT4[c][l4][v] (float4 = K-values 4l4..4l4+3). ----
__global__ void k0_t4(const float* __restrict__ sd, const float* __restrict__ vt,
                      float4* __restrict__ sdpT4) {
    int i = blockIdx.x * 256 + threadIdx.x;
    if (i >= 3 * NL4 * VP) return;
    int c   = i / (NL4 * VP);
    int rem = i - c * (NL4 * VP);
    int l4  = rem / VP;
    int v   = rem - l4 * VP;
    float4 out = make_float4(0.f, 0.f, 0.f, 0.f);
    if (v < VN) {
        int row = v * 3 + c;
        float vals[4];
#pragma unroll
        for (int q = 0; q < 4; q++) {
            int ll = l4 * 4 + q;
            vals[q] = (ll < NBETA) ? sd[row * NBETA + ll]
                     : ((ll == NBETA) ? vt[row] : 0.f);
        }
        out = make_float4(vals[0], vals[1], vals[2], vals[3]);
    }
    sdpT4[i] = out;   // consecutive i -> consecutive v: coalesced write
}

// ---- K1: JS[j3c][4*l4+q] = sum_v jr[j,v] * sdpT4[c][l4][v].q ----
__global__ void k1_t4(const float* __restrict__ jr, const float4* __restrict__ sdpT4,
                      float* __restrict__ JS) {
    int j3c = blockIdx.x, l4 = blockIdx.y;
    int j = j3c / 3, c = j3c - 3 * j;
    int t = threadIdx.x;
    const float4* col = sdpT4 + (size_t)(c * NL4 + l4) * VP;
    float4 acc = make_float4(0.f, 0.f, 0.f, 0.f);
    for (int v = t; v < VN; v += 256) {
        float w = jr[j * VN + v];
        float4 s = col[v];
        acc.x += w * s.x; acc.y += w * s.y; acc.z += w * s.z; acc.w += w * s.w;
    }
    __shared__ float4 red[256];
    red[t] = acc; __syncthreads();
    for (int s = 128; s > 0; s >>= 1) {
        if (t < s) {
            red[t].x += red[t + s].x; red[t].y += red[t + s].y;
            red[t].z += red[t + s].z; red[t].w += red[t + s].w;
        }
        __syncthreads();
    }
    if (t == 0) {
        JS[j3c * NBP + l4 * 4 + 0] = red[0].x;
        JS[j3c * NBP + l4 * 4 + 1] = red[0].y;
        JS[j3c * NBP + l4 * 4 + 2] = red[0].z;
        JS[j3c * NBP + l4 * 4 + 3] = red[0].w;
    }
}

// ---- rodrigues (matches reference eps semantics) ----
__device__ __forceinline__ void rodrigues3(float x, float y, float z, float* R) {
    float ax = x + 1e-8f, ay = y + 1e-8f, az = z + 1e-8f;
    float ang = sqrtf(ax * ax + ay * ay + az * az);
    float inv = 1.0f / ang;
    float ux = x * inv, uy = y * inv, uz = z * inv;
    float co = cosf(ang), si = sinf(ang), t1 = 1.0f - co;
    float K[9] = {0.f, -uz, uy,  uz, 0.f, -ux,  -uy, ux, 0.f};
    float K2[9];
#pragma unroll
    for (int r = 0; r < 3; r++)
#pragma unroll
        for (int cc = 0; cc < 3; cc++) {
            float a = 0.f;
#pragma unroll
            for (int k = 0; k < 3; k++) a += K[r * 3 + k] * K[k * 3 + cc];
            K2[r * 3 + cc] = a;
        }
#pragma unroll
    for (int i = 0; i < 9; i++) {
        float e = (i == 0 || i == 4 || i == 8) ? 1.f : 0.f;
        R[i] = e + si * K[i] + t1 * K2[i];
    }
}

// ---- K2: per-batch betas (col150=1, col151=0), joints = JS.sB, chain, rel, pf9 ----
__global__ void k2_pose(const float* __restrict__ shp, const float* __restrict__ expr,
                        const float* __restrict__ pose, const float* __restrict__ JS,
                        float* __restrict__ betasF, float* __restrict__ pf9,
                        float* __restrict__ rel) {
    int b = blockIdx.x;
    int tt = threadIdx.x;
    __shared__ float sB[NBP];
    __shared__ float sJ[15];
    for (int l = tt; l < NBP; l += 64) {
        float val = 0.0f;
        if (l < 100) val = shp[b * 100 + l];
        else if (l < 150) val = expr[b * 50 + (l - 100)];
        else if (l == 150) val = 1.0f;   // picks up v_template / Jt columns
        sB[l] = val;
        betasF[b * NBP + l] = val;
    }
    __syncthreads();
    if (tt < 15) {
        float acc = 0.0f;
        const float* row = JS + tt * NBP;
        for (int l = 0; l < NBP; ++l) acc += row[l] * sB[l];
        sJ[tt] = acc;
    }
    __syncthreads();
    if (tt == 0) {
        float p[6];
#pragma unroll
        for (int i = 0; i < 6; i++) p[i] = pose[b * 6 + i];
        float R0[9], RJ[9];
        rodrigues3(p[0], p[1], p[2], R0);
        rodrigues3(p[3], p[4], p[5], RJ);
        float Jm[5][3];
#pragma unroll
        for (int jj = 0; jj < 5; jj++)
#pragma unroll
            for (int cc = 0; cc < 3; cc++) Jm[jj][cc] = sJ[jj * 3 + cc];
        float rj[5][3];
#pragma unroll
        for (int cc = 0; cc < 3; cc++) {
            rj[0][cc] = Jm[0][cc];
            rj[1][cc] = Jm[1][cc] - Jm[0][cc];
            rj[2][cc] = Jm[2][cc] - Jm[1][cc];
            rj[3][cc] = Jm[3][cc] - Jm[1][cc];
            rj[4][cc] = Jm[4][cc] - Jm[1][cc];
        }
        float tw[5][3];
#pragma unroll
        for (int cc = 0; cc < 3; cc++) tw[0][cc] = rj[0][cc];
#pragma unroll
        for (int cc = 0; cc < 3; cc++)
            tw[1][cc] = R0[cc * 3 + 0] * rj[1][0] + R0[cc * 3 + 1] * rj[1][1] + R0[cc * 3 + 2] * rj[1][2] + tw[0][cc];
#pragma unroll
        for (int jj = 2; jj < 5; jj++)
#pragma unroll
            for (int cc = 0; cc < 3; cc++)
                tw[jj][cc] = R0[cc * 3 + 0] * rj[jj][0] + R0[cc * 3 + 1] * rj[jj][1] + R0[cc * 3 + 2] * rj[jj][2] + tw[1][cc];
        float R2w[9];
#pragma unroll
        for (int r = 0; r < 3; r++)
#pragma unroll
            for (int cc = 0; cc < 3; cc++) {
                float a = 0.f;
#pragma unroll
                for (int k = 0; k < 3; k++) a += R0[r * 3 + k] * RJ[k * 3 + cc];
                R2w[r * 3 + cc] = a;
            }
        float* ro = rel + b * 80;
#pragma unroll
        for (int jj = 0; jj < 5; jj++) {
            const float* Rw = (jj == 2) ? R2w : R0;
#pragma unroll
            for (int rr = 0; rr < 3; rr++) {
                ro[jj * 16 + rr * 4 + 0] = Rw[rr * 3 + 0];
                ro[jj * 16 + rr * 4 + 1] = Rw[rr * 3 + 1];
                ro[jj * 16 + rr * 4 + 2] = Rw[rr * 3 + 2];
                float tj = Rw[rr * 3 + 0] * Jm[jj][0] + Rw[rr * 3 + 1] * Jm[jj][1] + Rw[rr * 3 + 2] * Jm[jj][2];
                ro[jj * 16 + rr * 4 + 3] = tw[jj][rr] - tj;
            }
            ro[jj * 16 + 12] = 0.f; ro[jj * 16 + 13] = 0.f; ro[jj * 16 + 14] = 0.f; ro[jj * 16 + 15] = 1.f;
        }
        float* pf = pf9 + b * 12;
#pragma unroll
        for (int e = 0; e < 9; e++) pf[e] = RJ[e] - ((e == 0 || e == 4 || e == 8) ? 1.f : 0.f);
        pf[9] = 0.f; pf[10] = 0.f; pf[11] = 0.f;
    }
}

// ---- K3: fused GEMM + pose blend + LBS + T, no LDS, SW-pipelined sdp loads ----
// Best-measured configuration (round 18, 238.8 us total): launch_bounds(128,2)
// (spill-free), BT=16, transposed coalesced sdp panel, scalar betas loads,
// register double-buffer, epilogue loads after GEMM, fused T-store drain.
__global__ void __launch_bounds__(128, 2)
k3_main(const float4* __restrict__ sdpT4, const float* __restrict__ pd,
        const float* __restrict__ lw,
        const float* __restrict__ betasF, const float* __restrict__ pf9,
        const float* __restrict__ rel,
        float* __restrict__ outv, float* __restrict__ outT) {
    int tid = threadIdx.x;
    int v = blockIdx.x * 128 + tid;
    bool ok = v < VN;
    int vc = ok ? v : VN - 1;
    int b0 = blockIdx.y * BT;

    float acc[3][BT];
#pragma unroll
    for (int c = 0; c < 3; c++)
#pragma unroll
        for (int bb = 0; bb < BT; bb++) acc[c][bb] = 0.0f;

    const float4* sp = sdpT4 + vc;   // + (c*NL4 + l4)*VP walks K; lane walks v

    // prologue: prefetch iteration 0's tiles
    float4 nA0 = sp[(size_t)(0 * NL4 + 0) * VP];
    float4 nA1 = sp[(size_t)(0 * NL4 + 1) * VP];
    float4 nB0 = sp[(size_t)(1 * NL4 + 0) * VP];
    float4 nB1 = sp[(size_t)(1 * NL4 + 1) * VP];
    float4 nC0 = sp[(size_t)(2 * NL4 + 0) * VP];
    float4 nC1 = sp[(size_t)(2 * NL4 + 1) * VP];

#pragma unroll 1
    for (int l0 = 0; l0 < NBP; l0 += 8) {
        float4 a0 = nA0, a1 = nA1, b0q = nB0, b1q = nB1, c0q = nC0, c1q = nC1;
        int i0n = (l0 + 8 < NBP) ? ((l0 + 8) >> 2) : 0;   // dummy in-bounds prefetch on last iter
        nA0 = sp[(size_t)(0 * NL4 + i0n) * VP];
        nA1 = sp[(size_t)(0 * NL4 + i0n + 1) * VP];
        nB0 = sp[(size_t)(1 * NL4 + i0n) * VP];
        nB1 = sp[(size_t)(1 * NL4 + i0n + 1) * VP];
        nC0 = sp[(size_t)(2 * NL4 + i0n) * VP];
        nC1 = sp[(size_t)(2 * NL4 + i0n + 1) * VP];

        float s0[8] = {a0.x, a0.y, a0.z, a0.w, a1.x, a1.y, a1.z, a1.w};
        float s1[8] = {b0q.x, b0q.y, b0q.z, b0q.w, b1q.x, b1q.y, b1q.z, b1q.w};
        float s2[8] = {c0q.x, c0q.y, c0q.z, c0q.w, c1q.x, c1q.y, c1q.z, c1q.w};
#pragma unroll
        for (int bb = 0; bb < BT; bb++) {
            // uniform address -> scalar loads (SGPR path, K$)
            const float* brow = betasF + (size_t)(b0 + bb) * NBP + l0;
            const float4 be0 = *(const float4*)(brow);
            const float4 be1 = *(const float4*)(brow + 4);
            float be[8] = {be0.x, be0.y, be0.z, be0.w, be1.x, be1.y, be1.z, be1.w};
#pragma unroll
            for (int k = 0; k < 8; k++) {
                acc[0][bb] += be[k] * s0[k];
                acc[1][bb] += be[k] * s1[k];
                acc[2][bb] += be[k] * s2[k];
            }
        }
    }

    if (!ok) return;

    // per-lane epilogue inputs (vector loads), spill-safe placement (round 13)
    float wj[5], pdv[9][3];
#pragma unroll
    for (int j = 0; j < 5; j++) wj[j] = lw[v * 5 + j];
#pragma unroll
    for (int k = 0; k < 9; k++)
#pragma unroll
        for (int c = 0; c < 3; c++) pdv[k][c] = pd[(size_t)(9 + k) * N3 + v * 3 + c];

#pragma unroll    // full unroll: acc must stay register-indexed
    for (int bb = 0; bb < BT; bb++) {
        int b = b0 + bb;
        const float* pf = pf9 + b * 12;   // uniform -> scalar loads
        const float* rb = rel + b * 80;   // uniform -> scalar loads
        float vp[3];
#pragma unroll
        for (int c = 0; c < 3; c++) {
            float x = acc[c][bb];                     // = v_shaped (template folded in)
#pragma unroll
            for (int k = 0; k < 9; k++) x += pf[k] * pdv[k][c];
            vp[c] = x;
        }
        float T[16];
#pragma unroll
        for (int e = 0; e < 16; e++) T[e] = 0.0f;
#pragma unroll
        for (int j = 0; j < 5; j++) {
            float w = wj[j];
            const float4 r0 = *(const float4*)(rb + j * 16 + 0);
            const float4 r1 = *(const float4*)(rb + j * 16 + 4);
            const float4 r2 = *(const float4*)(rb + j * 16 + 8);
            const float4 r3 = *(const float4*)(rb + j * 16 + 12);
            T[0]  += w * r0.x;  T[1]  += w * r0.y;  T[2]  += w * r0.z;  T[3]  += w * r0.w;
            T[4]  += w * r1.x;  T[5]  += w * r1.y;  T[6]  += w * r1.z;  T[7]  += w * r1.w;
            T[8]  += w * r2.x;  T[9]  += w * r2.y;  T[10] += w * r2.z;  T[11] += w * r2.w;
            T[12] += w * r3.x;  T[13] += w * r3.y;  T[14] += w * r3.z;  T[15] += w * r3.w;
        }
        float vo[3];
#pragma unroll
        for (int rr = 0; rr < 3; rr++)
            vo[rr] = T[rr * 4 + 0] * vp[0] + T[rr * 4 + 1] * vp[1] + T[rr * 4 + 2] * vp[2] + T[rr * 4 + 3];

        size_t vbase = (size_t)b * VN + v;
        float* pv = outv + vbase * 3;
        pv[0] = vo[0];
        pv[1] = vo[1];
        pv[2] = vo[2];
        float4* pT = (float4*)(outT + vbase * 16);
        pT[0] = make_float4(T[0],  T[1],  T[2],  T[3]);
        pT[1] = make_float4(T[4],  T[5],  T[6],  T[7]);
        pT[2] = make_float4(T[8],  T[9],  T[10], T[11]);
        pT[3] = make_float4(T[12], T[13], T[14], T[15]);
    }
}

// ---------------- launch ----------------
extern "C" void kernel_launch(void* const* d_in, const int* in_sizes, int n_in,
                              void* d_out, int out_size, void* d_ws, size_t ws_size,
                              hipStream_t stream) {
    const float* shp  = (const float*)d_in[0];  // [1024,100]
    const float* expr = (const float*)d_in[1];  // [1024,50]
    const float* pose = (const float*)d_in[2];  // [1024,6]
    const float* vt   = (const float*)d_in[3];  // [5023,3]
    const float* sd   = (const float*)d_in[4];  // [5023,3,150]
    const float* pd   = (const float*)d_in[5];  // [36,15069]
    const float* jr   = (const float*)d_in[6];  // [5,5023]
    const float* lw   = (const float*)d_in[7];  // [5023,5]

    float* outv = (float*)d_out;
    float* outT = outv + (size_t)NBATCH * VN * 3;

    char* w = (char*)d_ws;
    const size_t SDPT_B  = (size_t)3 * NL4 * VP * 16;       // 9,163,776
    const size_t JS_B    = 15 * NBP * 4;                    // 9,120
    const size_t BETAS_B = (size_t)NBATCH * NBP * 4;        // 622,592
    const size_t PF9_B   = (size_t)NBATCH * 12 * 4;         // 49,152
    float4* sdpT4 = (float4*)w;
    float* JS     = (float*)(w + SDPT_B);
    float* betasF = (float*)(w + SDPT_B + JS_B);
    float* pf9    = (float*)(w + SDPT_B + JS_B + BETAS_B);
    float* rel    = (float*)(w + SDPT_B + JS_B + BETAS_B + PF9_B);

    k0_t4<<<(3 * NL4 * VP + 255) / 256, 256, 0, stream>>>(sd, vt, sdpT4);
    k1_t4<<<dim3(15, NL4), 256, 0, stream>>>(jr, sdpT4, JS);
    k2_pose<<<NBATCH, 64, 0, stream>>>(shp, expr, pose, JS, betasF, pf9, rel);
    k3_main<<<dim3(40, NBATCH / BT), 128, 0, stream>>>(sdpT4, pd, lw, betasF, pf9, rel, outv, outT);
}